// Round 2
// baseline (401.308 us; speedup 1.0000x reference)
//
#include <hip/hip_runtime.h>
#include <hip/hip_bf16.h>

#define N_NODES  20000
#define N_EDGES  320000
#define N_GRAPHS 512
#define D        256
#define TWO_D    512
#define EPS      1e-5f

// ---------------- kernels ----------------

__global__ __launch_bounds__(256) void init_h_kernel(const int* __restrict__ x,
                                                     const float* __restrict__ table,
                                                     float* __restrict__ h) {
    int i = blockIdx.x;         // node
    int d = threadIdx.x;        // feature
    h[i * D + d] = table[x[i] * D + d];
}

__global__ __launch_bounds__(256) void count_kernel(const int* __restrict__ dst,
                                                    int* __restrict__ counts) {
    int e = blockIdx.x * blockDim.x + threadIdx.x;
    if (e < N_EDGES) atomicAdd(&counts[dst[e]], 1);
}

// single block, 1024 threads: exclusive scan of counts -> offsets, plus dinv
__global__ __launch_bounds__(1024) void scan_kernel(const int* __restrict__ counts,
                                                    int* __restrict__ offsets,
                                                    float* __restrict__ dinv) {
    const int T = 1024;
    const int CH = (N_NODES + T - 1) / T;   // 20
    __shared__ int wsum[16];
    int t = threadIdx.x;
    int base = t * CH;
    int s = 0;
    for (int i = 0; i < CH; ++i) {
        int idx = base + i;
        if (idx < N_NODES) s += counts[idx];
    }
    int lane = t & 63, w = t >> 6;
    int v = s;
    for (int off = 1; off < 64; off <<= 1) {
        int u = __shfl_up(v, off);
        if (lane >= off) v += u;
    }
    if (lane == 63) wsum[w] = v;
    __syncthreads();
    if (t == 0) {
        int a = 0;
        for (int i = 0; i < 16; ++i) { int tmp = wsum[i]; wsum[i] = a; a += tmp; }
    }
    __syncthreads();
    int run = wsum[w] + (v - s);            // global exclusive prefix for this chunk
    for (int i = 0; i < CH; ++i) {
        int idx = base + i;
        if (idx < N_NODES) {
            offsets[idx] = run;
            int c = counts[idx];
            run += c;
            dinv[idx] = rsqrtf((float)(c + 1)); // +1 self-loop; deg>=1 always
        }
    }
    if (t == T - 1) offsets[N_NODES] = run;
}

__global__ __launch_bounds__(256) void scatter_kernel(const int* __restrict__ src,
                                                      const int* __restrict__ dst,
                                                      const int* __restrict__ offsets,
                                                      int* __restrict__ cursor,
                                                      const float* __restrict__ dinv,
                                                      int* __restrict__ csr_src,
                                                      float* __restrict__ csr_norm) {
    int e = blockIdx.x * blockDim.x + threadIdx.x;
    if (e >= N_EDGES) return;
    int d = dst[e], s = src[e];
    int p = atomicAdd(&cursor[d], 1);
    int idx = offsets[d] + p;
    csr_src[idx] = s;
    csr_norm[idx] = dinv[s] * dinv[d];
}

// one wave per dst node; 64 lanes x float4 = 256 floats
__global__ __launch_bounds__(256) void hop_kernel(const float* __restrict__ hin,
                                                  float* __restrict__ hout,
                                                  const int* __restrict__ offsets,
                                                  const int* __restrict__ csr_src,
                                                  const float* __restrict__ csr_norm,
                                                  const float* __restrict__ dinv) {
    int wid = (blockIdx.x * blockDim.x + threadIdx.x) >> 6;   // node
    if (wid >= N_NODES) return;
    int lane = threadIdx.x & 63;
    float dn = dinv[wid];
    float4 acc = ((const float4*)(hin + wid * D))[lane];
    float w0 = dn * dn;                                        // self-loop norm
    acc.x *= w0; acc.y *= w0; acc.z *= w0; acc.w *= w0;
    int e0 = offsets[wid], e1 = offsets[wid + 1];
    for (int e = e0; e < e1; ++e) {
        int s = csr_src[e];
        float w = csr_norm[e];
        float4 v = ((const float4*)(hin + s * D))[lane];
        acc.x += w * v.x; acc.y += w * v.y; acc.z += w * v.z; acc.w += w * v.w;
    }
    ((float4*)(hout + wid * D))[lane] = acc;
}

__global__ __launch_bounds__(256) void pool_kernel(const float* __restrict__ h,
                                                   const int* __restrict__ batch,
                                                   float* __restrict__ hg,
                                                   float* __restrict__ gcount) {
    int i = blockIdx.x;      // node
    int d = threadIdx.x;     // feature
    int g = batch[i];
    atomicAdd(&hg[g * D + d], h[i * D + d]);
    if (d == 0) atomicAdd(&gcount[g], 1.0f);
}

// hgl = hg @ sg_W + gcount * sg_b   (512 x 256) @ (256 x 256)
__global__ __launch_bounds__(256) void sg_linear_kernel(const float* __restrict__ hg,
                                                        const float* __restrict__ gcount,
                                                        const float* __restrict__ W,
                                                        const float* __restrict__ b,
                                                        float* __restrict__ out) {
    __shared__ float row[D];
    int g = blockIdx.x, j = threadIdx.x;
    row[j] = hg[g * D + j];
    __syncthreads();
    float acc = 0.f;
    for (int k = 0; k < D; ++k) acc += row[k] * W[k * D + j];
    out[g * D + j] = acc + gcount[g] * b[j];
}

// z1 = hgl @ W1 + b1   (512 x 256) @ (256 x 512)
__global__ __launch_bounds__(512) void mlp1_kernel(const float* __restrict__ in,
                                                   const float* __restrict__ W,
                                                   const float* __restrict__ b,
                                                   float* __restrict__ out) {
    __shared__ float row[D];
    int g = blockIdx.x, j = threadIdx.x;
    if (j < D) row[j] = in[g * D + j];
    __syncthreads();
    float acc = 0.f;
    for (int k = 0; k < D; ++k) acc += row[k] * W[k * TWO_D + j];
    out[g * TWO_D + j] = acc + b[j];
}

// z2 = z1r @ W2 + b2   (512 x 512) @ (512 x 256)
__global__ __launch_bounds__(256) void mlp2_kernel(const float* __restrict__ in,
                                                   const float* __restrict__ W,
                                                   const float* __restrict__ b,
                                                   float* __restrict__ out) {
    __shared__ float row[TWO_D];
    int g = blockIdx.x, j = threadIdx.x;
    row[j] = in[g * TWO_D + j];
    row[j + 256] = in[g * TWO_D + j + 256];
    __syncthreads();
    float acc = 0.f;
    for (int k = 0; k < TWO_D; ++k) acc += row[k] * W[k * D + j];
    out[g * D + j] = acc + b[j];
}

// training-mode batchnorm over rows (512 graphs) + relu, in place; one wave per column
template <int C>
__global__ __launch_bounds__(64) void bn_relu_kernel(float* __restrict__ z,
                                                     const float* __restrict__ gamma,
                                                     const float* __restrict__ beta) {
    int j = blockIdx.x;
    int lane = threadIdx.x;
    float s = 0.f, ss = 0.f;
    for (int r = lane; r < N_GRAPHS; r += 64) {
        float v = z[r * C + j];
        s += v; ss += v * v;
    }
    for (int off = 32; off; off >>= 1) { s += __shfl_down(s, off); ss += __shfl_down(ss, off); }
    s = __shfl(s, 0); ss = __shfl(ss, 0);
    float m = s / (float)N_GRAPHS;
    float var = ss / (float)N_GRAPHS - m * m;
    float inv = rsqrtf(var + EPS);
    float ga = gamma[j];
    float be = beta[j];
    for (int r = lane; r < N_GRAPHS; r += 64) {
        float v = (z[r * C + j] - m) * inv * ga + be;
        z[r * C + j] = v > 0.f ? v : 0.f;
    }
}

__global__ __launch_bounds__(64) void out_kernel(const float* __restrict__ z2,
                                                 const float* __restrict__ W3,
                                                 const float* __restrict__ b3,
                                                 float* __restrict__ out) {
    int g = blockIdx.x;
    int lane = threadIdx.x;
    float acc = 0.f;
    for (int k = lane; k < D; k += 64) acc += z2[g * D + k] * W3[k];
    for (int off = 32; off; off >>= 1) acc += __shfl_down(acc, off);
    if (lane == 0) out[g] = acc + b3[0];
}

// ---------------- launch ----------------

extern "C" void kernel_launch(void* const* d_in, const int* in_sizes, int n_in,
                              void* d_out, int out_size, void* d_ws, size_t ws_size,
                              hipStream_t stream) {
    const int*   x     = (const int*)d_in[0];
    const int*   ei    = (const int*)d_in[1];
    const int*   batch = (const int*)d_in[2];
    const float* table = (const float*)d_in[3];
    const float* sg_W  = (const float*)d_in[4];
    const float* sg_b  = (const float*)d_in[5];
    const float* W1    = (const float*)d_in[6];
    const float* b1    = (const float*)d_in[7];
    const float* g1    = (const float*)d_in[8];
    const float* be1   = (const float*)d_in[9];
    const float* W2    = (const float*)d_in[10];
    const float* b2    = (const float*)d_in[11];
    const float* g2    = (const float*)d_in[12];
    const float* be2   = (const float*)d_in[13];
    const float* W3    = (const float*)d_in[14];
    const float* b3    = (const float*)d_in[15];
    float*       out   = (float*)d_out;

    const int* e_src = ei;                // edge_index[0]
    const int* e_dst = ei + N_EDGES;      // edge_index[1]

    // workspace layout (16B aligned chunks)
    char* p = (char*)d_ws;
    auto alloc = [&](size_t bytes) { char* q = p; p += (bytes + 15) & ~size_t(15); return q; };
    float* h_a      = (float*)alloc((size_t)N_NODES * D * 4);
    float* h_b      = (float*)alloc((size_t)N_NODES * D * 4);
    int*   counts   = (int*)  alloc((size_t)N_NODES * 4);
    int*   offsets  = (int*)  alloc((size_t)(N_NODES + 1) * 4);
    int*   cursor   = (int*)  alloc((size_t)N_NODES * 4);
    float* dinv     = (float*)alloc((size_t)N_NODES * 4);
    int*   csr_src  = (int*)  alloc((size_t)N_EDGES * 4);
    float* csr_norm = (float*)alloc((size_t)N_EDGES * 4);
    float* hg       = (float*)alloc((size_t)N_GRAPHS * D * 4);
    float* gcount   = (float*)alloc((size_t)N_GRAPHS * 4);
    float* hgl      = (float*)alloc((size_t)N_GRAPHS * D * 4);
    float* z1       = (float*)alloc((size_t)N_GRAPHS * TWO_D * 4);
    float* z2       = (float*)alloc((size_t)N_GRAPHS * D * 4);

    hipMemsetAsync(counts, 0, (size_t)N_NODES * 4, stream);
    hipMemsetAsync(cursor, 0, (size_t)N_NODES * 4, stream);
    hipMemsetAsync(hg,     0, (size_t)N_GRAPHS * D * 4, stream);
    hipMemsetAsync(gcount, 0, (size_t)N_GRAPHS * 4, stream);

    init_h_kernel<<<N_NODES, 256, 0, stream>>>(x, table, h_a);
    count_kernel<<<(N_EDGES + 255) / 256, 256, 0, stream>>>(e_dst, counts);
    scan_kernel<<<1, 1024, 0, stream>>>(counts, offsets, dinv);
    scatter_kernel<<<(N_EDGES + 255) / 256, 256, 0, stream>>>(e_src, e_dst, offsets, cursor,
                                                              dinv, csr_src, csr_norm);

    const int HOP_BLOCKS = N_NODES / 4;   // 4 waves per 256-thread block
    hop_kernel<<<HOP_BLOCKS, 256, 0, stream>>>(h_a, h_b, offsets, csr_src, csr_norm, dinv);
    hop_kernel<<<HOP_BLOCKS, 256, 0, stream>>>(h_b, h_a, offsets, csr_src, csr_norm, dinv);
    hop_kernel<<<HOP_BLOCKS, 256, 0, stream>>>(h_a, h_b, offsets, csr_src, csr_norm, dinv);
    hop_kernel<<<HOP_BLOCKS, 256, 0, stream>>>(h_b, h_a, offsets, csr_src, csr_norm, dinv);

    pool_kernel<<<N_NODES, 256, 0, stream>>>(h_a, batch, hg, gcount);

    sg_linear_kernel<<<N_GRAPHS, 256, 0, stream>>>(hg, gcount, sg_W, sg_b, hgl);
    mlp1_kernel<<<N_GRAPHS, TWO_D, 0, stream>>>(hgl, W1, b1, z1);
    bn_relu_kernel<TWO_D><<<TWO_D, 64, 0, stream>>>(z1, g1, be1);
    mlp2_kernel<<<N_GRAPHS, D, 0, stream>>>(z1, W2, b2, z2);
    bn_relu_kernel<D><<<D, 64, 0, stream>>>(z2, g2, be2);
    out_kernel<<<N_GRAPHS, 64, 0, stream>>>(z2, W3, b3, out);
}

// Round 4
// 214.235 us; speedup vs baseline: 1.8732x; 1.8732x over previous
//
#include <hip/hip_runtime.h>
#include <hip/hip_bf16.h>

#define N_NODES  20000
#define N_EDGES  320000
#define N_GRAPHS 512
#define VOCAB    32
#define D        256
#define TWO_D    512
#define EPS      1e-5f

// ---------------- helpers ----------------

__device__ __forceinline__ int lower_bound_i(const int* __restrict__ a, int n, int v) {
    int lo = 0, hi = n;
    while (lo < hi) { int mid = (lo + hi) >> 1; if (a[mid] < v) lo = mid + 1; else hi = mid; }
    return lo;
}

// ---------------- CSR build ----------------

__global__ __launch_bounds__(256) void count_kernel(const int* __restrict__ dst,
                                                    int* __restrict__ counts) {
    int e = blockIdx.x * blockDim.x + threadIdx.x;
    if (e < N_EDGES) atomicAdd(&counts[dst[e]], 1);
}

// single block, 1024 threads: exclusive scan of counts -> offsets, plus dinv
__global__ __launch_bounds__(1024) void scan_kernel(const int* __restrict__ counts,
                                                    int* __restrict__ offsets,
                                                    float* __restrict__ dinv) {
    const int T = 1024;
    const int CH = (N_NODES + T - 1) / T;   // 20
    __shared__ int wsum[16];
    int t = threadIdx.x;
    int base = t * CH;
    int s = 0;
    for (int i = 0; i < CH; ++i) {
        int idx = base + i;
        if (idx < N_NODES) s += counts[idx];
    }
    int lane = t & 63, w = t >> 6;
    int v = s;
    for (int off = 1; off < 64; off <<= 1) {
        int u = __shfl_up(v, off);
        if (lane >= off) v += u;
    }
    if (lane == 63) wsum[w] = v;
    __syncthreads();
    if (t == 0) {
        int a = 0;
        for (int i = 0; i < 16; ++i) { int tmp = wsum[i]; wsum[i] = a; a += tmp; }
    }
    __syncthreads();
    int run = wsum[w] + (v - s);            // global exclusive prefix for this chunk
    for (int i = 0; i < CH; ++i) {
        int idx = base + i;
        if (idx < N_NODES) {
            offsets[idx] = run;
            int c = counts[idx];
            run += c;
            dinv[idx] = rsqrtf((float)(c + 1)); // +1 self-loop; deg>=1 always
        }
    }
    if (t == T - 1) offsets[N_NODES] = run;
}

__global__ __launch_bounds__(256) void scatter_kernel(const int* __restrict__ src,
                                                      const int* __restrict__ dst,
                                                      const int* __restrict__ offsets,
                                                      int* __restrict__ cursor,
                                                      const float* __restrict__ dinv,
                                                      int* __restrict__ csr_src,
                                                      float* __restrict__ csr_norm) {
    int e = blockIdx.x * blockDim.x + threadIdx.x;
    if (e >= N_EDGES) return;
    int d = dst[e], s = src[e];
    int p = atomicAdd(&cursor[d], 1);
    int idx = offsets[d] + p;
    csr_src[idx] = s;
    csr_norm[idx] = dinv[s] * dinv[d];
}

// ---------------- one-hot propagation ----------------

// M0[i][f] = (x[i] == f)
__global__ __launch_bounds__(256) void init_m_kernel(const int* __restrict__ x,
                                                     float* __restrict__ m) {
    int t = blockIdx.x * blockDim.x + threadIdx.x;   // t < N_NODES*32
    int i = t >> 5, f = t & 31;
    if (i < N_NODES) m[t] = (x[i] == f) ? 1.f : 0.f;
}

// one wave per dst node; features = 32 floats = 16 lanes x float2; 4 edges in parallel
__global__ __launch_bounds__(256) void hop32_kernel(const float* __restrict__ min_,
                                                    float* __restrict__ mout,
                                                    const int* __restrict__ offsets,
                                                    const int* __restrict__ csr_src,
                                                    const float* __restrict__ csr_norm,
                                                    const float* __restrict__ dinv) {
    int wid = (blockIdx.x * blockDim.x + threadIdx.x) >> 6;   // node
    if (wid >= N_NODES) return;
    int lane = threadIdx.x & 63;
    int q = lane >> 4;          // quarter 0..3 -> which edge of a group of 4
    int sub = lane & 15;        // float2 slot (feature pair)
    const float2* M2 = (const float2*)min_;
    float2 accA = make_float2(0.f, 0.f);
    float2 accB = make_float2(0.f, 0.f);
    int e0 = offsets[wid], e1 = offsets[wid + 1];
    for (int base = e0; base < e1; base += 64) {
        int n = min(64, e1 - base);
        int s_l = 0; float w_l = 0.f;
        if (lane < n) { s_l = csr_src[base + lane]; w_l = csr_norm[base + lane]; }
        for (int j = 0; j < n; j += 8) {
            int i1 = j + q, i2 = j + 4 + q;
            int   s1 = __shfl(s_l, i1);
            float w1 = __shfl(w_l, i1);
            int   s2 = __shfl(s_l, i2);
            float w2 = __shfl(w_l, i2);
            if (i1 < n) {
                float2 v = M2[s1 * 16 + sub];
                accA.x += w1 * v.x; accA.y += w1 * v.y;
            }
            if (i2 < n) {
                float2 v = M2[s2 * 16 + sub];
                accB.x += w2 * v.x; accB.y += w2 * v.y;
            }
        }
    }
    accA.x += accB.x; accA.y += accB.y;
    accA.x += __shfl_xor(accA.x, 16); accA.y += __shfl_xor(accA.y, 16);
    accA.x += __shfl_xor(accA.x, 32); accA.y += __shfl_xor(accA.y, 32);
    if (q == 0) {
        float dn = dinv[wid];
        float2 self = M2[wid * 16 + sub];
        accA.x += dn * dn * self.x;
        accA.y += dn * dn * self.y;
        ((float2*)mout)[wid * 16 + sub] = accA;
    }
}

// segment-sum pool over sorted batch: one 64-thread block per graph
__global__ __launch_bounds__(64) void pool32_kernel(const float* __restrict__ M,
                                                    const int* __restrict__ batch,
                                                    float* __restrict__ S,
                                                    float* __restrict__ gcount) {
    int g = blockIdx.x;
    int lo = lower_bound_i(batch, N_NODES, g);
    int hi = lower_bound_i(batch, N_NODES, g + 1);
    int lane = threadIdx.x;
    int f = lane & 31, r0 = lane >> 5;      // 2 rows in flight
    float s = 0.f;
    for (int i = lo + r0; i < hi; i += 2) s += M[i * 32 + f];
    s += __shfl_xor(s, 32);
    if (lane < 32) S[g * 32 + f] = s;
    if (lane == 0) gcount[g] = (float)(hi - lo);
}

// B1 = table(32x256) @ sg_W(256x256)
__global__ __launch_bounds__(256) void fold_kernel(const float* __restrict__ T,
                                                   const float* __restrict__ Wsg,
                                                   float* __restrict__ B1) {
    int r = blockIdx.x;      // 0..31
    int j = threadIdx.x;     // 0..255
    __shared__ float trow[D];
    trow[j] = T[r * D + j];
    __syncthreads();
    float acc = 0.f;
    for (int k = 0; k < D; ++k) acc += trow[k] * Wsg[k * D + j];
    B1[r * D + j] = acc;
}

// out[g][j] = sum_k in[g][k] * W[k][j] + bias   (G-tiled)
template <int K, int NOUT, int GT, int BIAS_COUNT>
__global__ __launch_bounds__(256) void linear_kernel(const float* __restrict__ in,
                                                     const float* __restrict__ W,
                                                     const float* __restrict__ bias,
                                                     const float* __restrict__ gcount,
                                                     float* __restrict__ out) {
    constexpr int JP = NOUT / 256;
    __shared__ float rows[GT * K];
    int g0 = blockIdx.x * GT;
    int tid = threadIdx.x;
    for (int idx = tid; idx < GT * K; idx += 256) rows[idx] = in[g0 * K + idx];
    __syncthreads();
    float acc[GT][JP];
#pragma unroll
    for (int i = 0; i < GT; ++i)
#pragma unroll
        for (int jp = 0; jp < JP; ++jp) acc[i][jp] = 0.f;
    for (int k = 0; k < K; ++k) {
        float wv[JP];
#pragma unroll
        for (int jp = 0; jp < JP; ++jp) wv[jp] = W[k * NOUT + tid + jp * 256];
#pragma unroll
        for (int i = 0; i < GT; ++i) {
            float r = rows[i * K + k];   // LDS broadcast
#pragma unroll
            for (int jp = 0; jp < JP; ++jp) acc[i][jp] += r * wv[jp];
        }
    }
#pragma unroll
    for (int i = 0; i < GT; ++i)
#pragma unroll
        for (int jp = 0; jp < JP; ++jp) {
            int j = tid + jp * 256;
            float bb = bias[j];
            float extra = BIAS_COUNT ? gcount[g0 + i] * bb : bb;
            out[(g0 + i) * NOUT + j] = acc[i][jp] + extra;
        }
}

// training-mode batchnorm over rows (512 graphs) + relu, in place; one wave per column
template <int C>
__global__ __launch_bounds__(64) void bn_relu_kernel(float* __restrict__ z,
                                                     const float* __restrict__ gamma,
                                                     const float* __restrict__ beta) {
    int j = blockIdx.x;
    int lane = threadIdx.x;
    float s = 0.f, ss = 0.f;
    for (int r = lane; r < N_GRAPHS; r += 64) {
        float v = z[r * C + j];
        s += v; ss += v * v;
    }
    for (int off = 32; off; off >>= 1) { s += __shfl_down(s, off); ss += __shfl_down(ss, off); }
    s = __shfl(s, 0); ss = __shfl(ss, 0);
    float m = s / (float)N_GRAPHS;
    float var = ss / (float)N_GRAPHS - m * m;
    float inv = rsqrtf(var + EPS);
    float ga = gamma[j];
    float be = beta[j];
    for (int r = lane; r < N_GRAPHS; r += 64) {
        float v = (z[r * C + j] - m) * inv * ga + be;
        z[r * C + j] = v > 0.f ? v : 0.f;
    }
}

__global__ __launch_bounds__(64) void out_kernel(const float* __restrict__ z2,
                                                 const float* __restrict__ W3,
                                                 const float* __restrict__ b3,
                                                 float* __restrict__ out) {
    int g = blockIdx.x;
    int lane = threadIdx.x;
    float acc = 0.f;
    for (int k = lane; k < D; k += 64) acc += z2[g * D + k] * W3[k];
    for (int off = 32; off; off >>= 1) acc += __shfl_down(acc, off);
    if (lane == 0) out[g] = acc + b3[0];
}

// ---------------- launch ----------------

extern "C" void kernel_launch(void* const* d_in, const int* in_sizes, int n_in,
                              void* d_out, int out_size, void* d_ws, size_t ws_size,
                              hipStream_t stream) {
    const int*   x     = (const int*)d_in[0];
    const int*   ei    = (const int*)d_in[1];
    const int*   batch = (const int*)d_in[2];
    const float* table = (const float*)d_in[3];
    const float* sg_W  = (const float*)d_in[4];
    const float* sg_b  = (const float*)d_in[5];
    const float* W1    = (const float*)d_in[6];
    const float* b1    = (const float*)d_in[7];
    const float* g1    = (const float*)d_in[8];
    const float* be1   = (const float*)d_in[9];
    const float* W2    = (const float*)d_in[10];
    const float* b2    = (const float*)d_in[11];
    const float* g2    = (const float*)d_in[12];
    const float* be2   = (const float*)d_in[13];
    const float* W3    = (const float*)d_in[14];
    const float* b3    = (const float*)d_in[15];
    float*       out   = (float*)d_out;

    const int* e_src = ei;                // edge_index[0]
    const int* e_dst = ei + N_EDGES;      // edge_index[1]

    // workspace layout (16B aligned chunks)
    char* p = (char*)d_ws;
    auto alloc = [&](size_t bytes) { char* q = p; p += (bytes + 15) & ~size_t(15); return q; };
    float* m_a      = (float*)alloc((size_t)N_NODES * VOCAB * 4);
    float* m_b      = (float*)alloc((size_t)N_NODES * VOCAB * 4);
    int*   counts   = (int*)  alloc((size_t)N_NODES * 4);
    int*   offsets  = (int*)  alloc((size_t)(N_NODES + 1) * 4);
    int*   cursor   = (int*)  alloc((size_t)N_NODES * 4);
    float* dinv     = (float*)alloc((size_t)N_NODES * 4);
    int*   csr_src  = (int*)  alloc((size_t)N_EDGES * 4);
    float* csr_norm = (float*)alloc((size_t)N_EDGES * 4);
    float* S        = (float*)alloc((size_t)N_GRAPHS * VOCAB * 4);
    float* gcount   = (float*)alloc((size_t)N_GRAPHS * 4);
    float* B1       = (float*)alloc((size_t)VOCAB * D * 4);
    float* hgl      = (float*)alloc((size_t)N_GRAPHS * D * 4);
    float* z1       = (float*)alloc((size_t)N_GRAPHS * TWO_D * 4);
    float* z2       = (float*)alloc((size_t)N_GRAPHS * D * 4);

    hipMemsetAsync(counts, 0, (size_t)N_NODES * 4, stream);
    hipMemsetAsync(cursor, 0, (size_t)N_NODES * 4, stream);

    // CSR build
    count_kernel<<<(N_EDGES + 255) / 256, 256, 0, stream>>>(e_dst, counts);
    scan_kernel<<<1, 1024, 0, stream>>>(counts, offsets, dinv);
    scatter_kernel<<<(N_EDGES + 255) / 256, 256, 0, stream>>>(e_src, e_dst, offsets, cursor,
                                                              dinv, csr_src, csr_norm);

    // fold table @ sg_W (independent of graph structure)
    fold_kernel<<<VOCAB, 256, 0, stream>>>(table, sg_W, B1);

    // one-hot init + 4 hops on [N x 32]
    init_m_kernel<<<(N_NODES * VOCAB + 255) / 256, 256, 0, stream>>>(x, m_a);
    const int HOP_BLOCKS = N_NODES / 4;   // 4 waves per 256-thread block
    hop32_kernel<<<HOP_BLOCKS, 256, 0, stream>>>(m_a, m_b, offsets, csr_src, csr_norm, dinv);
    hop32_kernel<<<HOP_BLOCKS, 256, 0, stream>>>(m_b, m_a, offsets, csr_src, csr_norm, dinv);
    hop32_kernel<<<HOP_BLOCKS, 256, 0, stream>>>(m_a, m_b, offsets, csr_src, csr_norm, dinv);
    hop32_kernel<<<HOP_BLOCKS, 256, 0, stream>>>(m_b, m_a, offsets, csr_src, csr_norm, dinv);

    // pool (sorted batch -> segment sums, no atomics)
    pool32_kernel<<<N_GRAPHS, 64, 0, stream>>>(m_a, batch, S, gcount);

    // hgl = S @ B1 + gcount * sg_b
    linear_kernel<VOCAB, D, 8, 1><<<N_GRAPHS / 8, 256, 0, stream>>>(S, B1, sg_b, gcount, hgl);
    // MLP tail
    linear_kernel<D, TWO_D, 4, 0><<<N_GRAPHS / 4, 256, 0, stream>>>(hgl, W1, b1, gcount, z1);
    bn_relu_kernel<TWO_D><<<TWO_D, 64, 0, stream>>>(z1, g1, be1);
    linear_kernel<TWO_D, D, 4, 0><<<N_GRAPHS / 4, 256, 0, stream>>>(z1, W2, b2, gcount, z2);
    bn_relu_kernel<D><<<D, 64, 0, stream>>>(z2, g2, be2);
    out_kernel<<<N_GRAPHS, 64, 0, stream>>>(z2, W3, b3, out);
}

// Round 5
// 212.316 us; speedup vs baseline: 1.8901x; 1.0090x over previous
//
#include <hip/hip_runtime.h>
#include <hip/hip_bf16.h>

#define N_NODES  20000
#define N_EDGES  320000
#define N_GRAPHS 512
#define VOCAB    32
#define D        256
#define TWO_D    512
#define EPS      1e-5f

// ---------------- helpers ----------------

__device__ __forceinline__ int lower_bound_i(const int* __restrict__ a, int n, int v) {
    int lo = 0, hi = n;
    while (lo < hi) { int mid = (lo + hi) >> 1; if (a[mid] < v) lo = mid + 1; else hi = mid; }
    return lo;
}

// ---------------- CSR build ----------------

__global__ __launch_bounds__(256) void zero_counts_kernel(int* __restrict__ counts) {
    int i = blockIdx.x * blockDim.x + threadIdx.x;
    if (i < N_NODES) counts[i] = 0;
}

__global__ __launch_bounds__(256) void count_kernel(const int* __restrict__ dst,
                                                    int* __restrict__ counts) {
    int e = blockIdx.x * blockDim.x + threadIdx.x;
    if (e < N_EDGES) atomicAdd(&counts[dst[e]], 1);
}

// single block, 1024 threads: exclusive scan of counts -> offsets (+cursor copy), plus dinv
__global__ __launch_bounds__(1024) void scan_kernel(const int* __restrict__ counts,
                                                    int* __restrict__ offsets,
                                                    int* __restrict__ cursor,
                                                    float* __restrict__ dinv) {
    const int T = 1024;
    const int CH = (N_NODES + T - 1) / T;   // 20
    __shared__ int wsum[16];
    int t = threadIdx.x;
    int base = t * CH;
    int s = 0;
    for (int i = 0; i < CH; ++i) {
        int idx = base + i;
        if (idx < N_NODES) s += counts[idx];
    }
    int lane = t & 63, w = t >> 6;
    int v = s;
    for (int off = 1; off < 64; off <<= 1) {
        int u = __shfl_up(v, off);
        if (lane >= off) v += u;
    }
    if (lane == 63) wsum[w] = v;
    __syncthreads();
    if (t == 0) {
        int a = 0;
        for (int i = 0; i < 16; ++i) { int tmp = wsum[i]; wsum[i] = a; a += tmp; }
    }
    __syncthreads();
    int run = wsum[w] + (v - s);            // global exclusive prefix for this chunk
    for (int i = 0; i < CH; ++i) {
        int idx = base + i;
        if (idx < N_NODES) {
            offsets[idx] = run;
            cursor[idx]  = run;             // scatter uses this as its running index
            int c = counts[idx];
            run += c;
            dinv[idx] = rsqrtf((float)(c + 1)); // +1 self-loop; deg>=1 always
        }
    }
    if (t == T - 1) offsets[N_NODES] = run;
}

// packed edge: {src, norm bits}
__global__ __launch_bounds__(256) void scatter_kernel(const int* __restrict__ src,
                                                      const int* __restrict__ dst,
                                                      int* __restrict__ cursor,
                                                      const float* __restrict__ dinv,
                                                      int2* __restrict__ edges) {
    int e = blockIdx.x * blockDim.x + threadIdx.x;
    if (e >= N_EDGES) return;
    int d = dst[e], s = src[e];
    int idx = atomicAdd(&cursor[d], 1);
    edges[idx] = make_int2(s, __float_as_int(dinv[s] * dinv[d]));
}

// ---------------- one-hot propagation ----------------

// hop 1 specialized: input row of src is onehot(x[src]); quarter-wave per node
__global__ __launch_bounds__(256) void hop1_kernel(const int* __restrict__ x,
                                                   float* __restrict__ mout,
                                                   const int* __restrict__ offsets,
                                                   const int2* __restrict__ edges,
                                                   const float* __restrict__ dinv) {
    int node = (blockIdx.x << 4) | (threadIdx.x >> 4);   // grid exact: 1250*16 = 20000
    int sub = threadIdx.x & 15;
    int f0 = sub * 2, f1 = f0 + 1;
    float dn = dinv[node];
    int xf = x[node];
    float2 acc = make_float2(xf == f0 ? dn * dn : 0.f,
                             xf == f1 ? dn * dn : 0.f);
    int e = offsets[node], e1 = offsets[node + 1];
    for (; e < e1; ++e) {
        int2 p = edges[e];
        float w = __int_as_float(p.y);
        int fs = x[p.x];
        acc.x += (fs == f0) ? w : 0.f;
        acc.y += (fs == f1) ? w : 0.f;
    }
    ((float2*)mout)[node * 16 + sub] = acc;
}

// general hop: quarter-wave (16 lanes) per node, float2 per lane, 2-edge ILP
__global__ __launch_bounds__(256) void hop_kernel(const float* __restrict__ min_,
                                                  float* __restrict__ mout,
                                                  const int* __restrict__ offsets,
                                                  const int2* __restrict__ edges,
                                                  const float* __restrict__ dinv) {
    int node = (blockIdx.x << 4) | (threadIdx.x >> 4);
    int sub = threadIdx.x & 15;
    const float2* M2 = (const float2*)min_;
    float dn = dinv[node];
    float2 self = M2[node * 16 + sub];
    float2 acc0 = make_float2(dn * dn * self.x, dn * dn * self.y);
    float2 acc1 = make_float2(0.f, 0.f);
    int e = offsets[node], e1 = offsets[node + 1];
    for (; e + 2 <= e1; e += 2) {
        int2 p0 = edges[e];
        int2 p1 = edges[e + 1];
        float w0 = __int_as_float(p0.y);
        float w1 = __int_as_float(p1.y);
        float2 v0 = M2[p0.x * 16 + sub];
        float2 v1 = M2[p1.x * 16 + sub];
        acc0.x += w0 * v0.x; acc0.y += w0 * v0.y;
        acc1.x += w1 * v1.x; acc1.y += w1 * v1.y;
    }
    if (e < e1) {
        int2 p0 = edges[e];
        float w0 = __int_as_float(p0.y);
        float2 v0 = M2[p0.x * 16 + sub];
        acc0.x += w0 * v0.x; acc0.y += w0 * v0.y;
    }
    acc0.x += acc1.x; acc0.y += acc1.y;
    ((float2*)mout)[node * 16 + sub] = acc0;
}

// segment-sum pool over sorted batch: one 64-thread block per graph
__global__ __launch_bounds__(64) void pool32_kernel(const float* __restrict__ M,
                                                    const int* __restrict__ batch,
                                                    float* __restrict__ S,
                                                    float* __restrict__ gcount) {
    int g = blockIdx.x;
    int lo = lower_bound_i(batch, N_NODES, g);
    int hi = lower_bound_i(batch, N_NODES, g + 1);
    int lane = threadIdx.x;
    int f = lane & 31, r0 = lane >> 5;      // 2 rows in flight
    float s = 0.f;
    for (int i = lo + r0; i < hi; i += 2) s += M[i * 32 + f];
    s += __shfl_xor(s, 32);
    if (lane < 32) S[g * 32 + f] = s;
    if (lane == 0) gcount[g] = (float)(hi - lo);
}

// ---------------- weight folding (graph-independent) ----------------

// F = table(32x256) @ sg_W(256x256)
__global__ __launch_bounds__(256) void fold1_kernel(const float* __restrict__ T,
                                                    const float* __restrict__ Wsg,
                                                    float* __restrict__ F) {
    int r = blockIdx.x;      // 0..31
    int j = threadIdx.x;     // 0..255
    __shared__ float trow[D];
    trow[j] = T[r * D + j];
    __syncthreads();
    float acc = 0.f;
    for (int k = 0; k < D; ++k) acc += trow[k] * Wsg[k * D + j];
    F[r * D + j] = acc;
}

// G = F(32x256) @ W1(256x512); u = sg_b @ W1 (block 32)
__global__ __launch_bounds__(512) void fold2_kernel(const float* __restrict__ F,
                                                    const float* __restrict__ sg_b,
                                                    const float* __restrict__ W1,
                                                    float* __restrict__ G,
                                                    float* __restrict__ u) {
    int r = blockIdx.x;      // 0..32
    int j = threadIdx.x;     // 0..511
    __shared__ float row[D];
    const float* srcrow = (r < VOCAB) ? (F + r * D) : sg_b;
    if (j < D) row[j] = srcrow[j];
    __syncthreads();
    float acc = 0.f;
    for (int k = 0; k < D; ++k) acc += row[k] * W1[k * TWO_D + j];
    float* dstrow = (r < VOCAB) ? (G + r * TWO_D) : u;
    dstrow[j] = acc;
}

// z1 = S(512x32) @ G(32x512) + gcount*u + b1
__global__ __launch_bounds__(256) void lin1_kernel(const float* __restrict__ S,
                                                   const float* __restrict__ G,
                                                   const float* __restrict__ u,
                                                   const float* __restrict__ b1,
                                                   const float* __restrict__ gcount,
                                                   float* __restrict__ z1) {
    __shared__ float rows[8 * VOCAB];          // 8 graphs per block
    int g0 = blockIdx.x * 8;
    int tid = threadIdx.x;
    rows[tid] = S[g0 * VOCAB + tid];           // 256 = 8*32 exactly
    __syncthreads();
    float acc[8][2];
#pragma unroll
    for (int i = 0; i < 8; ++i) { acc[i][0] = 0.f; acc[i][1] = 0.f; }
    for (int k = 0; k < VOCAB; ++k) {
        float w0 = G[k * TWO_D + tid];
        float w1 = G[k * TWO_D + tid + 256];
#pragma unroll
        for (int i = 0; i < 8; ++i) {
            float r = rows[i * VOCAB + k];
            acc[i][0] += r * w0;
            acc[i][1] += r * w1;
        }
    }
    float u0 = u[tid], u1 = u[tid + 256];
    float c0 = b1[tid], c1 = b1[tid + 256];
#pragma unroll
    for (int i = 0; i < 8; ++i) {
        float gc = gcount[g0 + i];
        z1[(g0 + i) * TWO_D + tid]       = acc[i][0] + gc * u0 + c0;
        z1[(g0 + i) * TWO_D + tid + 256] = acc[i][1] + gc * u1 + c1;
    }
}

// out[g][j] = sum_k in[g][k] * W[k][j] + bias   (G-tiled)
template <int K, int NOUT, int GT>
__global__ __launch_bounds__(256) void linear_kernel(const float* __restrict__ in,
                                                     const float* __restrict__ W,
                                                     const float* __restrict__ bias,
                                                     float* __restrict__ out) {
    constexpr int JP = NOUT / 256;
    __shared__ float rows[GT * K];
    int g0 = blockIdx.x * GT;
    int tid = threadIdx.x;
    for (int idx = tid; idx < GT * K; idx += 256) rows[idx] = in[g0 * K + idx];
    __syncthreads();
    float acc[GT][JP];
#pragma unroll
    for (int i = 0; i < GT; ++i)
#pragma unroll
        for (int jp = 0; jp < JP; ++jp) acc[i][jp] = 0.f;
    for (int k = 0; k < K; ++k) {
        float wv[JP];
#pragma unroll
        for (int jp = 0; jp < JP; ++jp) wv[jp] = W[k * NOUT + tid + jp * 256];
#pragma unroll
        for (int i = 0; i < GT; ++i) {
            float r = rows[i * K + k];   // LDS broadcast
#pragma unroll
            for (int jp = 0; jp < JP; ++jp) acc[i][jp] += r * wv[jp];
        }
    }
#pragma unroll
    for (int i = 0; i < GT; ++i)
#pragma unroll
        for (int jp = 0; jp < JP; ++jp) {
            int j = tid + jp * 256;
            out[(g0 + i) * NOUT + j] = acc[i][jp] + bias[j];
        }
}

// training-mode batchnorm over rows (512 graphs) + relu, in place; one wave per column
template <int C>
__global__ __launch_bounds__(64) void bn_relu_kernel(float* __restrict__ z,
                                                     const float* __restrict__ gamma,
                                                     const float* __restrict__ beta) {
    int j = blockIdx.x;
    int lane = threadIdx.x;
    float s = 0.f, ss = 0.f;
    for (int r = lane; r < N_GRAPHS; r += 64) {
        float v = z[r * C + j];
        s += v; ss += v * v;
    }
    for (int off = 32; off; off >>= 1) { s += __shfl_down(s, off); ss += __shfl_down(ss, off); }
    s = __shfl(s, 0); ss = __shfl(ss, 0);
    float m = s / (float)N_GRAPHS;
    float var = ss / (float)N_GRAPHS - m * m;
    float inv = rsqrtf(var + EPS);
    float ga = gamma[j];
    float be = beta[j];
    for (int r = lane; r < N_GRAPHS; r += 64) {
        float v = (z[r * C + j] - m) * inv * ga + be;
        z[r * C + j] = v > 0.f ? v : 0.f;
    }
}

__global__ __launch_bounds__(64) void out_kernel(const float* __restrict__ z2,
                                                 const float* __restrict__ W3,
                                                 const float* __restrict__ b3,
                                                 float* __restrict__ out) {
    int g = blockIdx.x;
    int lane = threadIdx.x;
    float acc = 0.f;
    for (int k = lane; k < D; k += 64) acc += z2[g * D + k] * W3[k];
    for (int off = 32; off; off >>= 1) acc += __shfl_down(acc, off);
    if (lane == 0) out[g] = acc + b3[0];
}

// ---------------- launch ----------------

extern "C" void kernel_launch(void* const* d_in, const int* in_sizes, int n_in,
                              void* d_out, int out_size, void* d_ws, size_t ws_size,
                              hipStream_t stream) {
    const int*   x     = (const int*)d_in[0];
    const int*   ei    = (const int*)d_in[1];
    const int*   batch = (const int*)d_in[2];
    const float* table = (const float*)d_in[3];
    const float* sg_W  = (const float*)d_in[4];
    const float* sg_b  = (const float*)d_in[5];
    const float* W1    = (const float*)d_in[6];
    const float* b1    = (const float*)d_in[7];
    const float* g1    = (const float*)d_in[8];
    const float* be1   = (const float*)d_in[9];
    const float* W2    = (const float*)d_in[10];
    const float* b2    = (const float*)d_in[11];
    const float* g2    = (const float*)d_in[12];
    const float* be2   = (const float*)d_in[13];
    const float* W3    = (const float*)d_in[14];
    const float* b3    = (const float*)d_in[15];
    float*       out   = (float*)d_out;

    const int* e_src = ei;                // edge_index[0]
    const int* e_dst = ei + N_EDGES;      // edge_index[1]

    // workspace layout (16B aligned chunks)
    char* p = (char*)d_ws;
    auto alloc = [&](size_t bytes) { char* q = p; p += (bytes + 15) & ~size_t(15); return q; };
    float* m_a      = (float*)alloc((size_t)N_NODES * VOCAB * 4);
    float* m_b      = (float*)alloc((size_t)N_NODES * VOCAB * 4);
    int*   counts   = (int*)  alloc((size_t)N_NODES * 4);
    int*   offsets  = (int*)  alloc((size_t)(N_NODES + 1) * 4);
    int*   cursor   = (int*)  alloc((size_t)N_NODES * 4);
    float* dinv     = (float*)alloc((size_t)N_NODES * 4);
    int2*  edges    = (int2*) alloc((size_t)N_EDGES * 8);
    float* S        = (float*)alloc((size_t)N_GRAPHS * VOCAB * 4);
    float* gcount   = (float*)alloc((size_t)N_GRAPHS * 4);
    float* F        = (float*)alloc((size_t)VOCAB * D * 4);
    float* G        = (float*)alloc((size_t)VOCAB * TWO_D * 4);
    float* u        = (float*)alloc((size_t)TWO_D * 4);
    float* z1       = (float*)alloc((size_t)N_GRAPHS * TWO_D * 4);
    float* z2       = (float*)alloc((size_t)N_GRAPHS * D * 4);

    // CSR build (no runtime memsets — zero via kernel, cursor seeded by scan)
    zero_counts_kernel<<<(N_NODES + 255) / 256, 256, 0, stream>>>(counts);
    count_kernel<<<(N_EDGES + 255) / 256, 256, 0, stream>>>(e_dst, counts);
    scan_kernel<<<1, 1024, 0, stream>>>(counts, offsets, cursor, dinv);
    scatter_kernel<<<(N_EDGES + 255) / 256, 256, 0, stream>>>(e_src, e_dst, cursor, dinv, edges);

    // weight folding (independent of graph structure)
    fold1_kernel<<<VOCAB, 256, 0, stream>>>(table, sg_W, F);
    fold2_kernel<<<VOCAB + 1, 512, 0, stream>>>(F, sg_b, W1, G, u);

    // 4 hops on [N x 32] one-hot space
    const int HB = N_NODES / 16;          // 1250 blocks, quarter-wave per node
    hop1_kernel<<<HB, 256, 0, stream>>>(x, m_a, offsets, edges, dinv);
    hop_kernel <<<HB, 256, 0, stream>>>(m_a, m_b, offsets, edges, dinv);
    hop_kernel <<<HB, 256, 0, stream>>>(m_b, m_a, offsets, edges, dinv);
    hop_kernel <<<HB, 256, 0, stream>>>(m_a, m_b, offsets, edges, dinv);

    // pool (sorted batch -> segment sums, no atomics)
    pool32_kernel<<<N_GRAPHS, 64, 0, stream>>>(m_b, batch, S, gcount);

    // z1 = S@G + gcount*u + b1, then BN+ReLU
    lin1_kernel<<<N_GRAPHS / 8, 256, 0, stream>>>(S, G, u, b1, gcount, z1);
    bn_relu_kernel<TWO_D><<<TWO_D, 64, 0, stream>>>(z1, g1, be1);
    // z2 = z1@W2 + b2, BN+ReLU
    linear_kernel<TWO_D, D, 4><<<N_GRAPHS / 4, 256, 0, stream>>>(z1, W2, b2, z2);
    bn_relu_kernel<D><<<D, 64, 0, stream>>>(z2, g2, be2);
    out_kernel<<<N_GRAPHS, 64, 0, stream>>>(z2, W3, b3, out);
}